// Round 10
// baseline (70.099 us; speedup 1.0000x reference)
//
#include <hip/hip_runtime.h>

#define HH 256
#define WW 256
#define HWSZ (HH*WW)
#define CC 64
#define GG 4
#define GC 16
#define KK 3
#define PP 9
#define NB 2
#define NBG (NB*GG)            // 8 (b,g) slices
#define NBLK_RP (NBG*HH)       // 2048 repack blocks
#define NBLK_MAIN (NBG*1024)   // 8192 main blocks (64 pixels x 4 lanes each)

typedef float f32x4 __attribute__((ext_vector_type(4)));

// ---------- Kernel 1: planar -> channels-last repack (per (b,g): [y][x][16]) ----------
__global__ __launch_bounds__(256) void repack_kernel(
    const float* __restrict__ img, float* __restrict__ pk)
{
    int bid = blockIdx.x;
    int y  = bid & (HH - 1);
    int bg = bid >> 8;
    int g  = bg & (GG - 1);
    int b  = bg >> 2;
    int x  = threadIdx.x;

    const float* src = img + (size_t)(b*CC + g*GC) * HWSZ + y*WW + x;
    float v[GC];
#pragma unroll
    for (int c = 0; c < GC; ++c) v[c] = src[c*HWSZ];

    float4* dst = (float4*)(pk + ((size_t)bg*HWSZ + y*WW + x) * GC);
#pragma unroll
    for (int q = 0; q < 4; ++q)
        dst[q] = make_float4(v[4*q], v[4*q+1], v[4*q+2], v[4*q+3]);
}

// ---------- Kernel 2: LDS-dedup'd math + depth-4 asm gather pipeline ----------
// Phase 1: 576 (pixel,tap) jobs over 256 threads -> folded weights + clamped
//          byte-offsets once per pixel, in LDS.
// Phase 2: 4 lanes/pixel; 4-slot rotating gather buffer (16 loads in flight,
//          counted vmcnt(12)) + double-buffered LDS prefetch (W/O of tap p+1
//          issued one phase early). F(p-4) precedes L(p) in-slot -> no hazard.
// launch_bounds stays (256,4): asm-load dest regs must not spill (round-7).
__global__ __launch_bounds__(256, 4) void misc_filter_coop(
    const float* __restrict__ pk,
    const float* __restrict__ kv,
    const float* __restrict__ kh,
    const float* __restrict__ off,
    const float* __restrict__ wgt,
    float* __restrict__ out)
{
    // XCD swizzle: 8192 blocks / 8 XCDs -> each XCD exactly one (b,g) slice.
    int phys = blockIdx.x;
    int logical = (phys & 7) * (NBLK_MAIN / 8) + (phys >> 3);
    int bg  = logical >> 10;          // 1024 blocks per (b,g)
    int blk = logical & 1023;
    int g   = bg & (GG - 1);
    int b   = bg >> 2;

    int t  = threadIdx.x;
    const int pixbase = blk * 64;

    __shared__ float Wlds[PP][64][4];   // folded corner weights
    __shared__ int   Olds[PP][64][4];   // corner byte offsets (pre-quadrant)

    const float* offb = off + (size_t)(b*GG*PP*2 + g*PP*2) * HWSZ + pixbase;
    const float* wgtb = wgt + (size_t)(b*GG*PP   + g*PP  ) * HWSZ + pixbase;
    const float* khb  = kh  + (size_t)(b*GG*KK   + g*KK  ) * HWSZ + pixbase;
    const float* kvb  = kv  + (size_t)(b*KK) * HWSZ + pixbase;

    // ---- Phase 1: per-(pixel,tap) math, computed once, shared via LDS ----
    for (int j = t; j < 64*PP; j += 256) {
        int px  = j & 63;
        int tap = j >> 6;
        int kx  = (tap * 11) >> 5;          // tap/3 for tap<9
        int ky  = tap - 3*kx;
        int pixel1 = pixbase + px;
        int yy = pixel1 >> 8;
        int xx = pixel1 & (WW - 1);

        float ox  = offb[(2*tap  )*HWSZ + px];
        float oy  = offb[(2*tap+1)*HWSZ + px];
        float wv  = wgtb[tap*HWSZ + px];
        float khv = khb[kx*HWSZ + px];
        float kvv = kvb[ky*HWSZ + px];
        float wp  = wv * (khv * kvv);

        float ux = (float)(xx + kx - 1) + ox;
        float uy = (float)(yy + ky - 1) + oy;
        float fx = floorf(ux), fy = floorf(uy);
        float wx = ux - fx,    wy = uy - fy;
        int x0 = (int)fx, y0 = (int)fy;
        int x1 = x0 + 1,  y1 = y0 + 1;
        bool vx0 = (unsigned)x0 < (unsigned)WW;
        bool vx1 = (unsigned)x1 < (unsigned)WW;
        bool vy0 = (unsigned)y0 < (unsigned)HH;
        bool vy1 = (unsigned)y1 < (unsigned)HH;
        float w00 = (1.f-wx)*(1.f-wy)*wp; if (!(vx0 && vy0)) w00 = 0.f;
        float w01 =      wx *(1.f-wy)*wp; if (!(vx1 && vy0)) w01 = 0.f;
        float w10 = (1.f-wx)*     wy *wp; if (!(vx0 && vy1)) w10 = 0.f;
        float w11 =      wx *     wy *wp; if (!(vx1 && vy1)) w11 = 0.f;
        int x0c = min(max(x0, 0), WW-1), x1c = min(max(x1, 0), WW-1);
        int y0c = min(max(y0, 0), HH-1), y1c = min(max(y1, 0), HH-1);

        *(float4*)&Wlds[tap][px][0] = make_float4(w00, w01, w10, w11);
        *(int4*)&Olds[tap][px][0]   = make_int4((y0c*WW + x0c)*(GC*4),
                                                (y0c*WW + x1c)*(GC*4),
                                                (y1c*WW + x0c)*(GC*4),
                                                (y1c*WW + x1c)*(GC*4));
    }
    __syncthreads();

    // ---- Phase 2: gather + FMA pipeline ----
    int q  = t & 3;                   // channel quad
    int pi = t >> 2;                  // pixel within block [0,64)
    int pixel = pixbase + pi;

    const float* pkb = pk + (size_t)bg * HWSZ * GC;   // wave-uniform SGPR base
    const unsigned qoffb = (unsigned)q * 16u;

    float acc0 = 0.f, acc1 = 0.f, acc2 = 0.f, acc3 = 0.f;
    f32x4 wvb[2];         // LDS prefetch double-buffer: weights
    int4  ovb[2];         // LDS prefetch double-buffer: offsets
    f32x4 w4[4];          // folded weights, 4-slot rotation
    f32x4 vv[4][4];       // in-flight corner vectors, 4-slot rotation

#define GLOAD(dst, boff) \
    asm volatile("global_load_dwordx4 %0, %1, %2" \
                 : "=v"(dst) : "v"(boff), "s"(pkb) : "memory")

#define WAITV(N) do { \
    asm volatile("s_waitcnt vmcnt(" #N ")" ::: "memory"); \
    __builtin_amdgcn_sched_barrier(0); } while (0)

// issue next tap's LDS reads (consumed one phase later; compiler inserts the
// lgkm wait right before first use, by which point the read has landed)
#define LDSPREF(p) do { if ((p) < PP) {                                         \
    wvb[(p)&1] = *(const f32x4*)&Wlds[(p) < PP ? (p) : 0][pi][0];               \
    ovb[(p)&1] = *(const int4*)&Olds[(p) < PP ? (p) : 0][pi][0]; } } while (0)

#define TAP_L(p) do {                                                           \
    const int bi_ = (p) % 4;                                                    \
    w4[bi_] = wvb[(p)&1];                                                       \
    int4 ov_ = ovb[(p)&1];                                                      \
    GLOAD(vv[bi_][0], (unsigned)ov_.x + qoffb);                                 \
    GLOAD(vv[bi_][1], (unsigned)ov_.y + qoffb);                                 \
    GLOAD(vv[bi_][2], (unsigned)ov_.z + qoffb);                                 \
    GLOAD(vv[bi_][3], (unsigned)ov_.w + qoffb);                                 \
} while (0)

#define TAP_FMA(p) do {                                                         \
    const int bi_ = (p) % 4;                                                    \
    acc0 = fmaf(w4[bi_][0], vv[bi_][0][0], acc0);                               \
    acc1 = fmaf(w4[bi_][0], vv[bi_][0][1], acc1);                               \
    acc2 = fmaf(w4[bi_][0], vv[bi_][0][2], acc2);                               \
    acc3 = fmaf(w4[bi_][0], vv[bi_][0][3], acc3);                               \
    acc0 = fmaf(w4[bi_][1], vv[bi_][1][0], acc0);                               \
    acc1 = fmaf(w4[bi_][1], vv[bi_][1][1], acc1);                               \
    acc2 = fmaf(w4[bi_][1], vv[bi_][1][2], acc2);                               \
    acc3 = fmaf(w4[bi_][1], vv[bi_][1][3], acc3);                               \
    acc0 = fmaf(w4[bi_][2], vv[bi_][2][0], acc0);                               \
    acc1 = fmaf(w4[bi_][2], vv[bi_][2][1], acc1);                               \
    acc2 = fmaf(w4[bi_][2], vv[bi_][2][2], acc2);                               \
    acc3 = fmaf(w4[bi_][2], vv[bi_][2][3], acc3);                               \
    acc0 = fmaf(w4[bi_][3], vv[bi_][3][0], acc0);                               \
    acc1 = fmaf(w4[bi_][3], vv[bi_][3][1], acc1);                               \
    acc2 = fmaf(w4[bi_][3], vv[bi_][3][2], acc2);                               \
    acc3 = fmaf(w4[bi_][3], vv[bi_][3][3], acc3);                               \
} while (0)

    // prologue: fill LDS prefetch + 4 gather slots (16 loads in flight)
    LDSPREF(0);
    LDSPREF(1); TAP_L(0);
    LDSPREF(2); TAP_L(1);
    LDSPREF(3); TAP_L(2);
    LDSPREF(4); TAP_L(3);
    // steady state: prefetch p+1, retire tap p-4, gather tap p
    LDSPREF(5); WAITV(12); TAP_FMA(0); TAP_L(4);
    LDSPREF(6); WAITV(12); TAP_FMA(1); TAP_L(5);
    LDSPREF(7); WAITV(12); TAP_FMA(2); TAP_L(6);
    LDSPREF(8); WAITV(12); TAP_FMA(3); TAP_L(7);
                WAITV(12); TAP_FMA(4); TAP_L(8);
    // drain
    WAITV(12); TAP_FMA(5);
    WAITV(8);  TAP_FMA(6);
    WAITV(4);  TAP_FMA(7);
    WAITV(0);  TAP_FMA(8);

#undef GLOAD
#undef WAITV
#undef LDSPREF
#undef TAP_L
#undef TAP_FMA

    float* outp = out + (size_t)(b*CC + g*GC + q*4) * HWSZ + pixel;
    outp[0*HWSZ] = acc0;
    outp[1*HWSZ] = acc1;
    outp[2*HWSZ] = acc2;
    outp[3*HWSZ] = acc3;
}

// ---------- Fallback: direct planar kernel (if ws too small) ----------
__global__ __launch_bounds__(256) void misc_filter_direct(
    const float* __restrict__ img,
    const float* __restrict__ kv,
    const float* __restrict__ kh,
    const float* __restrict__ off,
    const float* __restrict__ wgt,
    float* __restrict__ out)
{
    int phys = blockIdx.x;
    int logical = (phys & 7) * (NBLK_RP / 8) + (phys >> 3);
    int y  = logical & (HH - 1);
    int bg = logical >> 8;
    int g  = bg & (GG - 1);
    int b  = bg >> 2;
    int x  = threadIdx.x;

    const float* imgp = img + (size_t)(b*CC + g*GC) * HWSZ;
    int pix = y*WW + x;
    const float* offp = off + (size_t)(b*GG*PP*2 + g*PP*2) * HWSZ + pix;
    const float* wgtp = wgt + (size_t)(b*GG*PP   + g*PP  ) * HWSZ + pix;
    const float* khp  = kh  + (size_t)(b*GG*KK   + g*KK  ) * HWSZ + pix;
    const float* kvp  = kv  + (size_t)(b*KK) * HWSZ + pix;

    float khr[KK], kvr[KK];
#pragma unroll
    for (int i = 0; i < KK; ++i) { khr[i] = khp[i*HWSZ]; kvr[i] = kvp[i*HWSZ]; }
    float acc[GC];
#pragma unroll
    for (int c = 0; c < GC; ++c) acc[c] = 0.f;

#pragma unroll
    for (int p = 0; p < PP; ++p) {
        const int kx = p / KK, ky = p % KK;
        float ox = offp[(2*p  )*HWSZ];
        float oy = offp[(2*p+1)*HWSZ];
        float wp = wgtp[p*HWSZ] * khr[kx] * kvr[ky];
        float ux = (float)(x + kx - 1) + ox;
        float uy = (float)(y + ky - 1) + oy;
        float fx = floorf(ux), fy = floorf(uy);
        float wx = ux - fx,    wy = uy - fy;
        int x0 = (int)fx, y0 = (int)fy;
        int x1 = x0 + 1,  y1 = y0 + 1;
        bool vx0 = (unsigned)x0 < (unsigned)WW;
        bool vx1 = (unsigned)x1 < (unsigned)WW;
        bool vy0 = (unsigned)y0 < (unsigned)HH;
        bool vy1 = (unsigned)y1 < (unsigned)HH;
        float w00 = (1.f-wx)*(1.f-wy)*wp; if (!(vx0 && vy0)) w00 = 0.f;
        float w01 =      wx *(1.f-wy)*wp; if (!(vx1 && vy0)) w01 = 0.f;
        float w10 = (1.f-wx)*     wy *wp; if (!(vx0 && vy1)) w10 = 0.f;
        float w11 =      wx *     wy *wp; if (!(vx1 && vy1)) w11 = 0.f;
        int x0c = min(max(x0, 0), WW-1), x1c = min(max(x1, 0), WW-1);
        int y0c = min(max(y0, 0), HH-1), y1c = min(max(y1, 0), HH-1);
        int i00 = y0c*WW + x0c, i01 = y0c*WW + x1c;
        int i10 = y1c*WW + x0c, i11 = y1c*WW + x1c;
#pragma unroll
        for (int c = 0; c < GC; ++c) {
            const float* pl = imgp + c*HWSZ;
            acc[c] = fmaf(w00, pl[i00], acc[c]);
            acc[c] = fmaf(w01, pl[i01], acc[c]);
            acc[c] = fmaf(w10, pl[i10], acc[c]);
            acc[c] = fmaf(w11, pl[i11], acc[c]);
        }
    }
    float* outp = out + (size_t)(b*CC + g*GC) * HWSZ + pix;
#pragma unroll
    for (int c = 0; c < GC; ++c) outp[c*HWSZ] = acc[c];
}

extern "C" void kernel_launch(void* const* d_in, const int* in_sizes, int n_in,
                              void* d_out, int out_size, void* d_ws, size_t ws_size,
                              hipStream_t stream) {
    const float* img = (const float*)d_in[0];
    const float* kv  = (const float*)d_in[1];
    const float* kh  = (const float*)d_in[2];
    const float* off = (const float*)d_in[3];
    const float* wgt = (const float*)d_in[4];
    float* out = (float*)d_out;

    const size_t need = (size_t)NBG * HWSZ * GC * sizeof(float);  // 33.5 MB
    if (ws_size >= need) {
        float* pk = (float*)d_ws;
        repack_kernel<<<dim3(NBLK_RP), dim3(WW), 0, stream>>>(img, pk);
        misc_filter_coop<<<dim3(NBLK_MAIN), dim3(256), 0, stream>>>(pk, kv, kh, off, wgt, out);
    } else {
        misc_filter_direct<<<dim3(NBLK_RP), dim3(WW), 0, stream>>>(img, kv, kh, off, wgt, out);
    }
}

// Round 11
// 67.403 us; speedup vs baseline: 1.0400x; 1.0400x over previous
//
#include <hip/hip_runtime.h>

#define HH 256
#define WW 256
#define HWSZ (HH*WW)
#define CC 64
#define GG 4
#define GC 16
#define KK 3
#define PP 9
#define NB 2
#define NBG (NB*GG)            // 8 (b,g) slices
#define NBLK_RP (NBG*HH)       // 2048 repack blocks
#define NBLK_MAIN (NBG*1024)   // 8192 main blocks (16x4 pixel tile x 4 lanes)

typedef float f32x4 __attribute__((ext_vector_type(4)));

// ---------- Kernel 1: planar -> channels-last repack (per (b,g): [y][x][16]) ----------
__global__ __launch_bounds__(256) void repack_kernel(
    const float* __restrict__ img, float* __restrict__ pk)
{
    int bid = blockIdx.x;
    int y  = bid & (HH - 1);
    int bg = bid >> 8;
    int g  = bg & (GG - 1);
    int b  = bg >> 2;
    int x  = threadIdx.x;

    const float* src = img + (size_t)(b*CC + g*GC) * HWSZ + y*WW + x;
    float v[GC];
#pragma unroll
    for (int c = 0; c < GC; ++c) v[c] = src[c*HWSZ];

    float4* dst = (float4*)(pk + ((size_t)bg*HWSZ + y*WW + x) * GC);
#pragma unroll
    for (int q = 0; q < 4; ++q)
        dst[q] = make_float4(v[4*q], v[4*q+1], v[4*q+2], v[4*q+3]);
}

// ---------- Kernel 2: 16x4 tile + LDS-dedup'd math + depth-4 asm pipeline ----------
// Tile = 16x4 pixels: the block's 2304 corner-gathers cluster in a ~24x12
// pixel-group region (~18KB) -> ~8x line reuse through L1 instead of random
// 64B requests across the whole 4MB slice (L2 random-BW was the r10 limiter).
// Phase 1: 576 (pixel,tap) jobs -> folded weights + byte offsets once, in LDS.
// Phase 2: 4 lanes/pixel; 4-slot rotating gather buffer, counted vmcnt(12).
// launch_bounds stays (256,4): asm-load dest regs must not spill (round-7).
__global__ __launch_bounds__(256, 4) void misc_filter_coop(
    const float* __restrict__ pk,
    const float* __restrict__ kv,
    const float* __restrict__ kh,
    const float* __restrict__ off,
    const float* __restrict__ wgt,
    float* __restrict__ out)
{
    // XCD swizzle: 8192 blocks / 8 XCDs -> each XCD exactly one (b,g) slice.
    int phys = blockIdx.x;
    int logical = (phys & 7) * (NBLK_MAIN / 8) + (phys >> 3);
    int bg  = logical >> 10;          // 1024 tiles per (b,g)
    int blk = logical & 1023;
    int g   = bg & (GG - 1);
    int b   = bg >> 2;

    // 16x4 tile: 16 across (tx in [0,16)), 64 down (ty in [0,64))
    int tx = blk & 15;
    int ty = blk >> 4;
    const int tilebase = ty*4*WW + tx*16;

    int t  = threadIdx.x;

    __shared__ float Wlds[PP][64][4];   // folded corner weights
    __shared__ int   Olds[PP][64][4];   // corner byte offsets (pre-quadrant)

    const float* offb = off + (size_t)(b*GG*PP*2 + g*PP*2) * HWSZ + tilebase;
    const float* wgtb = wgt + (size_t)(b*GG*PP   + g*PP  ) * HWSZ + tilebase;
    const float* khb  = kh  + (size_t)(b*GG*KK   + g*KK  ) * HWSZ + tilebase;
    const float* kvb  = kv  + (size_t)(b*KK) * HWSZ + tilebase;

    // ---- Phase 1: per-(pixel,tap) math, computed once, shared via LDS ----
    for (int j = t; j < 64*PP; j += 256) {
        int pidx = j & 63;                  // pixel within tile
        int col  = j & 15;
        int row  = (j >> 4) & 3;
        int tap  = j >> 6;
        int kx   = (tap * 11) >> 5;         // tap/3 for tap<9
        int ky   = tap - 3*kx;
        int pixoff = row*WW + col;
        int pixel1 = tilebase + pixoff;
        int yy = pixel1 >> 8;
        int xx = pixel1 & (WW - 1);

        float ox  = offb[(2*tap  )*HWSZ + pixoff];
        float oy  = offb[(2*tap+1)*HWSZ + pixoff];
        float wv  = wgtb[tap*HWSZ + pixoff];
        float khv = khb[kx*HWSZ + pixoff];
        float kvv = kvb[ky*HWSZ + pixoff];
        float wp  = wv * (khv * kvv);

        float ux = (float)(xx + kx - 1) + ox;
        float uy = (float)(yy + ky - 1) + oy;
        float fx = floorf(ux), fy = floorf(uy);
        float wx = ux - fx,    wy = uy - fy;
        int x0 = (int)fx, y0 = (int)fy;
        int x1 = x0 + 1,  y1 = y0 + 1;
        bool vx0 = (unsigned)x0 < (unsigned)WW;
        bool vx1 = (unsigned)x1 < (unsigned)WW;
        bool vy0 = (unsigned)y0 < (unsigned)HH;
        bool vy1 = (unsigned)y1 < (unsigned)HH;
        float w00 = (1.f-wx)*(1.f-wy)*wp; if (!(vx0 && vy0)) w00 = 0.f;
        float w01 =      wx *(1.f-wy)*wp; if (!(vx1 && vy0)) w01 = 0.f;
        float w10 = (1.f-wx)*     wy *wp; if (!(vx0 && vy1)) w10 = 0.f;
        float w11 =      wx *     wy *wp; if (!(vx1 && vy1)) w11 = 0.f;
        int x0c = min(max(x0, 0), WW-1), x1c = min(max(x1, 0), WW-1);
        int y0c = min(max(y0, 0), HH-1), y1c = min(max(y1, 0), HH-1);

        *(float4*)&Wlds[tap][pidx][0] = make_float4(w00, w01, w10, w11);
        *(int4*)&Olds[tap][pidx][0]   = make_int4((y0c*WW + x0c)*(GC*4),
                                                  (y0c*WW + x1c)*(GC*4),
                                                  (y1c*WW + x0c)*(GC*4),
                                                  (y1c*WW + x1c)*(GC*4));
    }
    __syncthreads();

    // ---- Phase 2: gather + FMA pipeline ----
    int q  = t & 3;                   // channel quad
    int pi = t >> 2;                  // pixel within tile [0,64)
    int pixel = tilebase + (pi >> 4)*WW + (pi & 15);

    const float* pkb = pk + (size_t)bg * HWSZ * GC;   // wave-uniform SGPR base
    const unsigned qoffb = (unsigned)q * 16u;

    float acc0 = 0.f, acc1 = 0.f, acc2 = 0.f, acc3 = 0.f;
    f32x4 wvb[2];         // LDS prefetch double-buffer: weights
    int4  ovb[2];         // LDS prefetch double-buffer: offsets
    f32x4 w4[4];          // folded weights, 4-slot rotation
    f32x4 vv[4][4];       // in-flight corner vectors, 4-slot rotation

#define GLOAD(dst, boff) \
    asm volatile("global_load_dwordx4 %0, %1, %2" \
                 : "=v"(dst) : "v"(boff), "s"(pkb) : "memory")

#define WAITV(N) do { \
    asm volatile("s_waitcnt vmcnt(" #N ")" ::: "memory"); \
    __builtin_amdgcn_sched_barrier(0); } while (0)

#define LDSPREF(p) do { if ((p) < PP) {                                         \
    wvb[(p)&1] = *(const f32x4*)&Wlds[(p) < PP ? (p) : 0][pi][0];               \
    ovb[(p)&1] = *(const int4*)&Olds[(p) < PP ? (p) : 0][pi][0]; } } while (0)

#define TAP_L(p) do {                                                           \
    const int bi_ = (p) % 4;                                                    \
    w4[bi_] = wvb[(p)&1];                                                       \
    int4 ov_ = ovb[(p)&1];                                                      \
    GLOAD(vv[bi_][0], (unsigned)ov_.x + qoffb);                                 \
    GLOAD(vv[bi_][1], (unsigned)ov_.y + qoffb);                                 \
    GLOAD(vv[bi_][2], (unsigned)ov_.z + qoffb);                                 \
    GLOAD(vv[bi_][3], (unsigned)ov_.w + qoffb);                                 \
} while (0)

#define TAP_FMA(p) do {                                                         \
    const int bi_ = (p) % 4;                                                    \
    acc0 = fmaf(w4[bi_][0], vv[bi_][0][0], acc0);                               \
    acc1 = fmaf(w4[bi_][0], vv[bi_][0][1], acc1);                               \
    acc2 = fmaf(w4[bi_][0], vv[bi_][0][2], acc2);                               \
    acc3 = fmaf(w4[bi_][0], vv[bi_][0][3], acc3);                               \
    acc0 = fmaf(w4[bi_][1], vv[bi_][1][0], acc0);                               \
    acc1 = fmaf(w4[bi_][1], vv[bi_][1][1], acc1);                               \
    acc2 = fmaf(w4[bi_][1], vv[bi_][1][2], acc2);                               \
    acc3 = fmaf(w4[bi_][1], vv[bi_][1][3], acc3);                               \
    acc0 = fmaf(w4[bi_][2], vv[bi_][2][0], acc0);                               \
    acc1 = fmaf(w4[bi_][2], vv[bi_][2][1], acc1);                               \
    acc2 = fmaf(w4[bi_][2], vv[bi_][2][2], acc2);                               \
    acc3 = fmaf(w4[bi_][2], vv[bi_][2][3], acc3);                               \
    acc0 = fmaf(w4[bi_][3], vv[bi_][3][0], acc0);                               \
    acc1 = fmaf(w4[bi_][3], vv[bi_][3][1], acc1);                               \
    acc2 = fmaf(w4[bi_][3], vv[bi_][3][2], acc2);                               \
    acc3 = fmaf(w4[bi_][3], vv[bi_][3][3], acc3);                               \
} while (0)

    // prologue: fill LDS prefetch + 4 gather slots (16 loads in flight)
    LDSPREF(0);
    LDSPREF(1); TAP_L(0);
    LDSPREF(2); TAP_L(1);
    LDSPREF(3); TAP_L(2);
    LDSPREF(4); TAP_L(3);
    // steady state: prefetch p+1, retire tap p-4, gather tap p
    LDSPREF(5); WAITV(12); TAP_FMA(0); TAP_L(4);
    LDSPREF(6); WAITV(12); TAP_FMA(1); TAP_L(5);
    LDSPREF(7); WAITV(12); TAP_FMA(2); TAP_L(6);
    LDSPREF(8); WAITV(12); TAP_FMA(3); TAP_L(7);
                WAITV(12); TAP_FMA(4); TAP_L(8);
    // drain
    WAITV(12); TAP_FMA(5);
    WAITV(8);  TAP_FMA(6);
    WAITV(4);  TAP_FMA(7);
    WAITV(0);  TAP_FMA(8);

#undef GLOAD
#undef WAITV
#undef LDSPREF
#undef TAP_L
#undef TAP_FMA

    float* outp = out + (size_t)(b*CC + g*GC + q*4) * HWSZ + pixel;
    outp[0*HWSZ] = acc0;
    outp[1*HWSZ] = acc1;
    outp[2*HWSZ] = acc2;
    outp[3*HWSZ] = acc3;
}

// ---------- Fallback: direct planar kernel (if ws too small) ----------
__global__ __launch_bounds__(256) void misc_filter_direct(
    const float* __restrict__ img,
    const float* __restrict__ kv,
    const float* __restrict__ kh,
    const float* __restrict__ off,
    const float* __restrict__ wgt,
    float* __restrict__ out)
{
    int phys = blockIdx.x;
    int logical = (phys & 7) * (NBLK_RP / 8) + (phys >> 3);
    int y  = logical & (HH - 1);
    int bg = logical >> 8;
    int g  = bg & (GG - 1);
    int b  = bg >> 2;
    int x  = threadIdx.x;

    const float* imgp = img + (size_t)(b*CC + g*GC) * HWSZ;
    int pix = y*WW + x;
    const float* offp = off + (size_t)(b*GG*PP*2 + g*PP*2) * HWSZ + pix;
    const float* wgtp = wgt + (size_t)(b*GG*PP   + g*PP  ) * HWSZ + pix;
    const float* khp  = kh  + (size_t)(b*GG*KK   + g*KK  ) * HWSZ + pix;
    const float* kvp  = kv  + (size_t)(b*KK) * HWSZ + pix;

    float khr[KK], kvr[KK];
#pragma unroll
    for (int i = 0; i < KK; ++i) { khr[i] = khp[i*HWSZ]; kvr[i] = kvp[i*HWSZ]; }
    float acc[GC];
#pragma unroll
    for (int c = 0; c < GC; ++c) acc[c] = 0.f;

#pragma unroll
    for (int p = 0; p < PP; ++p) {
        const int kx = p / KK, ky = p % KK;
        float ox = offp[(2*p  )*HWSZ];
        float oy = offp[(2*p+1)*HWSZ];
        float wp = wgtp[p*HWSZ] * khr[kx] * kvr[ky];
        float ux = (float)(x + kx - 1) + ox;
        float uy = (float)(y + ky - 1) + oy;
        float fx = floorf(ux), fy = floorf(uy);
        float wx = ux - fx,    wy = uy - fy;
        int x0 = (int)fx, y0 = (int)fy;
        int x1 = x0 + 1,  y1 = y0 + 1;
        bool vx0 = (unsigned)x0 < (unsigned)WW;
        bool vx1 = (unsigned)x1 < (unsigned)WW;
        bool vy0 = (unsigned)y0 < (unsigned)HH;
        bool vy1 = (unsigned)y1 < (unsigned)HH;
        float w00 = (1.f-wx)*(1.f-wy)*wp; if (!(vx0 && vy0)) w00 = 0.f;
        float w01 =      wx *(1.f-wy)*wp; if (!(vx1 && vy0)) w01 = 0.f;
        float w10 = (1.f-wx)*     wy *wp; if (!(vx0 && vy1)) w10 = 0.f;
        float w11 =      wx *     wy *wp; if (!(vx1 && vy1)) w11 = 0.f;
        int x0c = min(max(x0, 0), WW-1), x1c = min(max(x1, 0), WW-1);
        int y0c = min(max(y0, 0), HH-1), y1c = min(max(y1, 0), HH-1);
        int i00 = y0c*WW + x0c, i01 = y0c*WW + x1c;
        int i10 = y1c*WW + x0c, i11 = y1c*WW + x1c;
#pragma unroll
        for (int c = 0; c < GC; ++c) {
            const float* pl = imgp + c*HWSZ;
            acc[c] = fmaf(w00, pl[i00], acc[c]);
            acc[c] = fmaf(w01, pl[i01], acc[c]);
            acc[c] = fmaf(w10, pl[i10], acc[c]);
            acc[c] = fmaf(w11, pl[i11], acc[c]);
        }
    }
    float* outp = out + (size_t)(b*CC + g*GC) * HWSZ + pix;
#pragma unroll
    for (int c = 0; c < GC; ++c) outp[c*HWSZ] = acc[c];
}

extern "C" void kernel_launch(void* const* d_in, const int* in_sizes, int n_in,
                              void* d_out, int out_size, void* d_ws, size_t ws_size,
                              hipStream_t stream) {
    const float* img = (const float*)d_in[0];
    const float* kv  = (const float*)d_in[1];
    const float* kh  = (const float*)d_in[2];
    const float* off = (const float*)d_in[3];
    const float* wgt = (const float*)d_in[4];
    float* out = (float*)d_out;

    const size_t need = (size_t)NBG * HWSZ * GC * sizeof(float);  // 33.5 MB
    if (ws_size >= need) {
        float* pk = (float*)d_ws;
        repack_kernel<<<dim3(NBLK_RP), dim3(WW), 0, stream>>>(img, pk);
        misc_filter_coop<<<dim3(NBLK_MAIN), dim3(256), 0, stream>>>(pk, kv, kh, off, wgt, out);
    } else {
        misc_filter_direct<<<dim3(NBLK_RP), dim3(WW), 0, stream>>>(img, kv, kh, off, wgt, out);
    }
}